// Round 10
// baseline (3327.472 us; speedup 1.0000x reference)
//
#include <hip/hip_runtime.h>
#include <hip/hip_bf16.h>

#define IN_FEATS 22
#define HID 16
#define FCH 8
#define NG 256
#define NPB 1024      // nodes per bucket
#define NBLK 1024     // hist/scan chunks
#define PBLK 256      // partition blocks (each does NBLK/PBLK chunks)
#define CPB (NBLK / PBLK)

typedef __hip_bfloat16 bf16;

__device__ __forceinline__ void atomAddF(float* p, float v) {
#if defined(__HIP_PLATFORM_AMD__)
    unsafeAtomicAdd(p, v);
#else
    atomicAdd(p, v);
#endif
}

__device__ __forceinline__ float b2f(unsigned short v) {
    union { unsigned u; float f; } t; t.u = ((unsigned)v) << 16; return t.f;
}
__device__ __forceinline__ unsigned short f2b(float f) {
    __hip_bfloat16 h = __float2bfloat16(f);
    return *reinterpret_cast<unsigned short*>(&h);
}

// ---------------- input projection: y1 = h @ W1 (bf16 out) ----------------
__global__ __launch_bounds__(256) void proj1_kernel(
    const float* __restrict__ h, const float* __restrict__ W1,
    bf16* __restrict__ y1, int n) {
    int t = blockIdx.x * blockDim.x + threadIdx.x;
    int total = n * HID;
    int stride = gridDim.x * blockDim.x;
    for (int s = t; s < total; s += stride) {
        int node = s >> 4, f = s & 15;
        const float* hr = h + (long long)node * IN_FEATS;
        float acc = 0.f;
#pragma unroll
        for (int k = 0; k < IN_FEATS; ++k) acc += hr[k] * W1[k * HID + f];
        y1[s] = __float2bfloat16(acc);
    }
}

// ---------------- edge bucketing (radix partition by dst>>10) ----------------
__global__ __launch_bounds__(1024) void hist_kernel(
    const int* __restrict__ dst, int* __restrict__ histT,
    int ne, int NB, int chunk) {
    __shared__ int h[NPB];
    int blk = blockIdx.x, tid = threadIdx.x;
    for (int i = tid; i < NPB; i += 1024) h[i] = 0;
    __syncthreads();
    int s = blk * chunk;
    int e2 = min(s + chunk, ne);
    for (int e = s + tid; e < e2; e += 1024)
        atomicAdd(&h[((unsigned)dst[e]) >> 10], 1);
    __syncthreads();
    for (int b = tid; b < NB; b += 1024) histT[b * NBLK + blk] = h[b];
}

__global__ __launch_bounds__(256) void scan_block_kernel(
    const int* __restrict__ in, int* __restrict__ out,
    int* __restrict__ blockSums, int n) {
    __shared__ int s[256];
    int i = blockIdx.x * 256 + threadIdx.x;
    int v = (i < n) ? in[i] : 0;
    s[threadIdx.x] = v;
    __syncthreads();
    for (int off = 1; off < 256; off <<= 1) {
        int x = (threadIdx.x >= off) ? s[threadIdx.x - off] : 0;
        __syncthreads();
        s[threadIdx.x] += x;
        __syncthreads();
    }
    if (i < n) out[i] = s[threadIdx.x] - v;
    if (threadIdx.x == 255) blockSums[blockIdx.x] = s[255];
}

__global__ __launch_bounds__(1024) void scan_sums_kernel(
    int* __restrict__ blockSums, int nb) {
    __shared__ int s[1024];
    int t = threadIdx.x;
    int loc[4];
    int sum = 0;
#pragma unroll
    for (int k = 0; k < 4; ++k) {
        int idx = t * 4 + k;
        int v = (idx < nb) ? blockSums[idx] : 0;
        loc[k] = sum;
        sum += v;
    }
    s[t] = sum;
    __syncthreads();
    for (int off = 1; off < 1024; off <<= 1) {
        int x = (t >= off) ? s[t - off] : 0;
        __syncthreads();
        s[t] += x;
        __syncthreads();
    }
    int excl = s[t] - sum;
#pragma unroll
    for (int k = 0; k < 4; ++k) {
        int idx = t * 4 + k;
        if (idx < nb) blockSums[idx] = excl + loc[k];
    }
}

__global__ __launch_bounds__(256) void scan_add_kernel(
    int* __restrict__ data, const int* __restrict__ blockSums,
    int* __restrict__ histTT, int total) {
    int i = blockIdx.x * 256 + threadIdx.x;
    if (i < total) {
        int r = data[i] + blockSums[i >> 8];
        data[i] = r;                                    // scanned, bucket-major
        histTT[(i & (NBLK - 1)) * NPB + (i >> 10)] = r; // [chunk][bucket]
    }
}

// scatter edges into bucket-grouped 'packed' ((dstLocal<<20)|src).
// 256 blocks x 4 chunks: open-line footprint = 256*NB*64B ~= 16MB (fits L2
// aggregate) so lines are fully written before eviction.
__global__ __launch_bounds__(1024) void partition_kernel(
    const int* __restrict__ src, const int* __restrict__ dst,
    const int* __restrict__ histTT, int* __restrict__ packed,
    int ne, int NB, int chunk) {
    __shared__ int cur[NPB];
    int m = blockIdx.x, tid = threadIdx.x;
    for (int c = m * CPB; c < m * CPB + CPB; ++c) {
        for (int b = tid; b < NB; b += 1024) cur[b] = histTT[c * NPB + b];
        __syncthreads();
        int s = c * chunk, e2 = min(s + chunk, ne);
        for (int e = s + tid; e < e2; e += 1024) {
            int dn = dst[e];
            int bkt = ((unsigned)dn) >> 10;
            int pos = atomicAdd(&cur[bkt], 1);
            packed[pos] = ((dn & (NPB - 1)) << 20) | src[e];
        }
        __syncthreads();
    }
}

// fused GCN layer straight from 'packed' (no CSR): one block per bucket,
// LDS fp32 accumulator agg[1024][17] (16 feats + degree). 4 lanes per edge,
// unroll-2 -> 8 independent 32B gathers per quad in flight; 4 LDS atomics
// per lane per edge. Epilogue: mean + bias + relu (+ @W2 for layer 1).
template <bool PROJ>
__global__ __launch_bounds__(1024) void agg_lds_kernel(
    const int* __restrict__ rowoffE,   // scanned histT (bucket-major)
    const int* __restrict__ packed,
    const bf16* __restrict__ y, const float* __restrict__ bias,
    const float* __restrict__ W, bf16* __restrict__ out,
    int n, int ne, int NB) {
    __shared__ float agg[NPB * 17];
    __shared__ float wlds[256];
    int b = blockIdx.x, tid = threadIdx.x;
    if (PROJ && tid < 256) wlds[tid] = W[tid];
    for (int i = tid; i < NPB * 17; i += 1024) agg[i] = 0.f;
    __syncthreads();
    int start = rowoffE[b << 10];
    int end = (b + 1 < NB) ? rowoffE[(b + 1) << 10] : ne;
    int q = tid >> 2, c = tid & 3;
    int cc = c << 2;
    int e = start + q;
    for (; e + 256 < end; e += 512) {
        int pk0 = packed[e];
        int pk1 = packed[e + 256];
        int sn0 = pk0 & 0xFFFFF; unsigned dl0 = ((unsigned)pk0) >> 20;
        int sn1 = pk1 & 0xFFFFF; unsigned dl1 = ((unsigned)pk1) >> 20;
        ushort4 u0 = *(const ushort4*)(y + (sn0 << 4) + cc);
        ushort4 u1 = *(const ushort4*)(y + (sn1 << 4) + cc);
        float* a0 = &agg[dl0 * 17 + cc];
        float* a1 = &agg[dl1 * 17 + cc];
        atomicAdd(a0 + 0, b2f(u0.x)); atomicAdd(a0 + 1, b2f(u0.y));
        atomicAdd(a0 + 2, b2f(u0.z)); atomicAdd(a0 + 3, b2f(u0.w));
        atomicAdd(a1 + 0, b2f(u1.x)); atomicAdd(a1 + 1, b2f(u1.y));
        atomicAdd(a1 + 2, b2f(u1.z)); atomicAdd(a1 + 3, b2f(u1.w));
        if (c == 0) {
            atomicAdd(&agg[dl0 * 17 + 16], 1.f);
            atomicAdd(&agg[dl1 * 17 + 16], 1.f);
        }
    }
    for (; e < end; e += 256) {
        int pk = packed[e];
        int sn = pk & 0xFFFFF; unsigned dl = ((unsigned)pk) >> 20;
        ushort4 u = *(const ushort4*)(y + (sn << 4) + cc);
        float* a = &agg[dl * 17 + cc];
        atomicAdd(a + 0, b2f(u.x)); atomicAdd(a + 1, b2f(u.y));
        atomicAdd(a + 2, b2f(u.z)); atomicAdd(a + 3, b2f(u.w));
        if (c == 0) atomicAdd(&agg[dl * 17 + 16], 1.f);
    }
    __syncthreads();
    int nodeBase = b << 10;
    int cnt = min(NPB, n - nodeBase);
    if (tid < cnt) {
        int node = nodeBase + tid;
        float* ap = &agg[tid * 17];
        float dcount = ap[16];
        float x[HID];
        if (dcount > 0.f) {
            float inv = 1.f / dcount;
#pragma unroll
            for (int f = 0; f < HID; ++f)
                x[f] = fmaxf(ap[f] * inv + bias[f], 0.f);
        } else {
            const ushort4* yp = (const ushort4*)(y + ((long long)node << 4));
#pragma unroll
            for (int qq = 0; qq < 4; ++qq) {
                ushort4 u = yp[qq];
                x[qq * 4 + 0] = fmaxf(b2f(u.x) + bias[qq * 4 + 0], 0.f);
                x[qq * 4 + 1] = fmaxf(b2f(u.y) + bias[qq * 4 + 1], 0.f);
                x[qq * 4 + 2] = fmaxf(b2f(u.z) + bias[qq * 4 + 2], 0.f);
                x[qq * 4 + 3] = fmaxf(b2f(u.w) + bias[qq * 4 + 3], 0.f);
            }
        }
        ushort4* op = (ushort4*)(out + ((long long)node << 4));
        if (PROJ) {
            float o[HID];
#pragma unroll
            for (int f = 0; f < HID; ++f) o[f] = 0.f;
#pragma unroll
            for (int k = 0; k < HID; ++k) {
                float xv = x[k];
#pragma unroll
                for (int f = 0; f < HID; ++f) o[f] += xv * wlds[k * HID + f];
            }
#pragma unroll
            for (int qq = 0; qq < 4; ++qq) {
                ushort4 st;
                st.x = f2b(o[qq * 4 + 0]); st.y = f2b(o[qq * 4 + 1]);
                st.z = f2b(o[qq * 4 + 2]); st.w = f2b(o[qq * 4 + 3]);
                op[qq] = st;
            }
        } else {
#pragma unroll
            for (int qq = 0; qq < 4; ++qq) {
                ushort4 st;
                st.x = f2b(x[qq * 4 + 0]); st.y = f2b(x[qq * 4 + 1]);
                st.z = f2b(x[qq * 4 + 2]); st.w = f2b(x[qq * 4 + 3]);
                op[qq] = st;
            }
        }
    }
}

// ---------------- pooling + FC head (bf16 features in) ----------------
__global__ __launch_bounds__(256) void pool_fc_bf16_kernel(
    const bf16* __restrict__ x2, const int* __restrict__ gid, int n,
    const float* __restrict__ Wf1, const float* __restrict__ bf1,
    const float* __restrict__ Wf2, const float* __restrict__ bf2,
    float* __restrict__ out) {
    int g = blockIdx.x;
    int lo, hi;
    {
        int a = 0, b = n;
        while (a < b) { int m = (a + b) >> 1; if (gid[m] < g) a = m + 1; else b = m; }
        lo = a;
        b = n;
        while (a < b) { int m = (a + b) >> 1; if (gid[m] < g + 1) a = m + 1; else b = m; }
        hi = a;
    }
    int cnt = hi - lo;
    float acc[HID];
#pragma unroll
    for (int k = 0; k < HID; ++k) acc[k] = 0.f;
    for (int i = lo + threadIdx.x; i < hi; i += blockDim.x) {
        const uint4* p = (const uint4*)(x2 + (long long)i * HID);
#pragma unroll
        for (int q = 0; q < 2; ++q) {
            uint4 u = p[q];
            unsigned w[4] = {u.x, u.y, u.z, u.w};
#pragma unroll
            for (int c = 0; c < 4; ++c) {
                union { unsigned i; float f; } loV, hiV;
                loV.i = (w[c] & 0xFFFFu) << 16;
                hiV.i = w[c] & 0xFFFF0000u;
                acc[q * 8 + c * 2 + 0] += loV.f;
                acc[q * 8 + c * 2 + 1] += hiV.f;
            }
        }
    }
    __shared__ float smem[256][HID];
#pragma unroll
    for (int k = 0; k < HID; ++k) smem[threadIdx.x][k] = acc[k];
    __syncthreads();
    for (int off = 128; off > 0; off >>= 1) {
        if (threadIdx.x < off)
            for (int k = 0; k < HID; ++k)
                smem[threadIdx.x][k] += smem[threadIdx.x + off][k];
        __syncthreads();
    }
    if (threadIdx.x == 0) {
        float inv = cnt > 0 ? 1.f / (float)cnt : 0.f;
        float hg[HID];
        for (int k = 0; k < HID; ++k) hg[k] = smem[0][k] * inv;
        float f1[FCH];
        for (int j = 0; j < FCH; ++j) {
            float a = bf1[j];
            for (int k = 0; k < HID; ++k) a += hg[k] * Wf1[k * FCH + j];
            f1[j] = a;
        }
        float o = bf2[0];
        for (int j = 0; j < FCH; ++j) o += f1[j] * Wf2[j];
        out[g] = 1.f / (1.f + expf(-o));
    }
}

// ---------------- fallback: atomic-scatter path (fp32, proven R1) ----------
__global__ __launch_bounds__(256) void proj1_f32_kernel(
    const float* __restrict__ h, const float* __restrict__ W1,
    float* __restrict__ y1, int n) {
    int t = blockIdx.x * blockDim.x + threadIdx.x;
    int total = n * HID;
    int stride = gridDim.x * blockDim.x;
    for (int s = t; s < total; s += stride) {
        int node = s >> 4, f = s & 15;
        const float* hr = h + (long long)node * IN_FEATS;
        float acc = 0.f;
#pragma unroll
        for (int k = 0; k < IN_FEATS; ++k) acc += hr[k] * W1[k * HID + f];
        y1[s] = acc;
    }
}

template <bool COUNT_DEG>
__global__ __launch_bounds__(256) void scatter_kernel(
    const int* __restrict__ src, const int* __restrict__ dst,
    const float* __restrict__ y, float* __restrict__ agg,
    float* __restrict__ deg, int n_edges) {
    int t = blockIdx.x * blockDim.x + threadIdx.x;
    int total = n_edges * HID;
    int stride = gridDim.x * blockDim.x;
    for (int s = t; s < total; s += stride) {
        int e = s >> 4, f = s & 15;
        int sn = src[e], dn = dst[e];
        float v = y[(long long)sn * HID + f];
        atomAddF(&agg[(long long)dn * HID + f], v);
        if (COUNT_DEG && f == 0) atomAddF(&deg[dn], 1.0f);
    }
}

__global__ __launch_bounds__(256) void finish1_kernel(
    const float* __restrict__ agg, const float* __restrict__ deg,
    float* __restrict__ y, const float* __restrict__ b1,
    const float* __restrict__ W2, int n) {
    int i = blockIdx.x * blockDim.x + threadIdx.x;
    int stride = gridDim.x * blockDim.x;
    for (; i < n; i += stride) {
        float d = deg[i];
        float inv = d > 0.f ? 1.f / d : 0.f;
        bool mail = d > 0.f;
        const float4* ag = (const float4*)(agg + (long long)i * HID);
        const float4* yy = (const float4*)(y + (long long)i * HID);
        float x1[HID];
#pragma unroll
        for (int q = 0; q < 4; ++q) {
            float4 a = ag[q];
            float4 b = yy[q];
            float v0 = mail ? a.x * inv : b.x;
            float v1 = mail ? a.y * inv : b.y;
            float v2 = mail ? a.z * inv : b.z;
            float v3 = mail ? a.w * inv : b.w;
            x1[q * 4 + 0] = fmaxf(v0 + b1[q * 4 + 0], 0.f);
            x1[q * 4 + 1] = fmaxf(v1 + b1[q * 4 + 1], 0.f);
            x1[q * 4 + 2] = fmaxf(v2 + b1[q * 4 + 2], 0.f);
            x1[q * 4 + 3] = fmaxf(v3 + b1[q * 4 + 3], 0.f);
        }
        float out[HID];
#pragma unroll
        for (int f = 0; f < HID; ++f) out[f] = 0.f;
#pragma unroll
        for (int k = 0; k < HID; ++k) {
            float xv = x1[k];
#pragma unroll
            for (int f = 0; f < HID; ++f) out[f] += xv * W2[k * HID + f];
        }
        float4* dst4 = (float4*)(y + (long long)i * HID);
#pragma unroll
        for (int q = 0; q < 4; ++q)
            dst4[q] = make_float4(out[q * 4 + 0], out[q * 4 + 1],
                                  out[q * 4 + 2], out[q * 4 + 3]);
    }
}

__global__ __launch_bounds__(256) void finish2_kernel(
    const float* __restrict__ agg, const float* __restrict__ deg,
    float* __restrict__ y, const float* __restrict__ b2, int n) {
    int i = blockIdx.x * blockDim.x + threadIdx.x;
    int stride = gridDim.x * blockDim.x;
    for (; i < n; i += stride) {
        float d = deg[i];
        float inv = d > 0.f ? 1.f / d : 0.f;
        bool mail = d > 0.f;
        const float4* ag = (const float4*)(agg + (long long)i * HID);
        float4* yy = (float4*)(y + (long long)i * HID);
#pragma unroll
        for (int q = 0; q < 4; ++q) {
            float4 a = ag[q];
            float4 b = yy[q];
            float v0 = mail ? a.x * inv : b.x;
            float v1 = mail ? a.y * inv : b.y;
            float v2 = mail ? a.z * inv : b.z;
            float v3 = mail ? a.w * inv : b.w;
            yy[q] = make_float4(fmaxf(v0 + b2[q * 4 + 0], 0.f),
                                fmaxf(v1 + b2[q * 4 + 1], 0.f),
                                fmaxf(v2 + b2[q * 4 + 2], 0.f),
                                fmaxf(v3 + b2[q * 4 + 3], 0.f));
        }
    }
}

__global__ __launch_bounds__(256) void pool_fc_f32_kernel(
    const float* __restrict__ x2, const int* __restrict__ gid, int n,
    const float* __restrict__ Wf1, const float* __restrict__ bf1,
    const float* __restrict__ Wf2, const float* __restrict__ bf2,
    float* __restrict__ out) {
    int g = blockIdx.x;
    int lo, hi;
    {
        int a = 0, b = n;
        while (a < b) { int m = (a + b) >> 1; if (gid[m] < g) a = m + 1; else b = m; }
        lo = a;
        b = n;
        while (a < b) { int m = (a + b) >> 1; if (gid[m] < g + 1) a = m + 1; else b = m; }
        hi = a;
    }
    int cnt = hi - lo;
    float acc[HID];
#pragma unroll
    for (int k = 0; k < HID; ++k) acc[k] = 0.f;
    for (int i = lo + threadIdx.x; i < hi; i += blockDim.x) {
        const float4* p = (const float4*)(x2 + (long long)i * HID);
#pragma unroll
        for (int q = 0; q < 4; ++q) {
            float4 v = p[q];
            acc[q * 4 + 0] += v.x; acc[q * 4 + 1] += v.y;
            acc[q * 4 + 2] += v.z; acc[q * 4 + 3] += v.w;
        }
    }
    __shared__ float smem[256][HID];
#pragma unroll
    for (int k = 0; k < HID; ++k) smem[threadIdx.x][k] = acc[k];
    __syncthreads();
    for (int off = 128; off > 0; off >>= 1) {
        if (threadIdx.x < off)
            for (int k = 0; k < HID; ++k)
                smem[threadIdx.x][k] += smem[threadIdx.x + off][k];
        __syncthreads();
    }
    if (threadIdx.x == 0) {
        float inv = cnt > 0 ? 1.f / (float)cnt : 0.f;
        float hg[HID];
        for (int k = 0; k < HID; ++k) hg[k] = smem[0][k] * inv;
        float f1[FCH];
        for (int j = 0; j < FCH; ++j) {
            float a = bf1[j];
            for (int k = 0; k < HID; ++k) a += hg[k] * Wf1[k * FCH + j];
            f1[j] = a;
        }
        float o = bf2[0];
        for (int j = 0; j < FCH; ++j) o += f1[j] * Wf2[j];
        out[g] = 1.f / (1.f + expf(-o));
    }
}

extern "C" void kernel_launch(void* const* d_in, const int* in_sizes, int n_in,
                              void* d_out, int out_size, void* d_ws, size_t ws_size,
                              hipStream_t stream) {
    const float* h   = (const float*)d_in[0];
    const int*   src = (const int*)d_in[1];
    const int*   dst = (const int*)d_in[2];
    const int*   gid = (const int*)d_in[3];
    const float* W1  = (const float*)d_in[4];
    const float* b1  = (const float*)d_in[5];
    const float* W2  = (const float*)d_in[6];
    const float* b2  = (const float*)d_in[7];
    const float* Wf1 = (const float*)d_in[8];
    const float* bf1 = (const float*)d_in[9];
    const float* Wf2 = (const float*)d_in[10];
    const float* bf2 = (const float*)d_in[11];
    float* out = (float*)d_out;

    int n  = in_sizes[3];
    int ne = in_sizes[1];

    size_t featB16 = (size_t)n * HID * 2;        // 32 MB (bf16 features)
    size_t featB32 = (size_t)n * HID * 4;        // 64 MB (fallback)
    size_t edgeB   = (size_t)ne * 4;             // 64 MB
    int NB  = (n + NPB - 1) / NPB;
    int NBS = NB * NBLK;
    int nbS = (NBS + 255) / 256;

    size_t off_bufA   = 0;
    size_t off_bufB   = off_bufA + featB16;
    size_t off_packed = off_bufB + featB16;      // persists through both layers
    size_t off_histT  = off_packed + edgeB;
    size_t off_histTT = off_histT + (size_t)NBS * 4;
    size_t off_bsums  = off_histTT + (size_t)NPB * NBLK * 4;
    size_t need       = off_bsums + 4096 * 4;

    char* ws = (char*)d_ws;
    if (ws_size >= need && n <= (1 << 20) && NB <= NPB && nbS <= 4096) {
        // ---------- radix-bucket + LDS-accumulate path (no CSR) ----------
        bf16*  bufA   = (bf16*)(ws + off_bufA);
        bf16*  bufB   = (bf16*)(ws + off_bufB);
        int*   packed = (int*) (ws + off_packed);
        int*   histT  = (int*) (ws + off_histT);
        int*   histTT = (int*) (ws + off_histTT);
        int*   bsums  = (int*) (ws + off_bsums);

        int chunk = (ne + NBLK - 1) / NBLK;

        proj1_kernel<<<4096, 256, 0, stream>>>(h, W1, bufA, n);
        hist_kernel<<<NBLK, 1024, 0, stream>>>(dst, histT, ne, NB, chunk);
        scan_block_kernel<<<nbS, 256, 0, stream>>>(histT, histT, bsums, NBS);
        scan_sums_kernel<<<1, 1024, 0, stream>>>(bsums, nbS);
        scan_add_kernel<<<nbS, 256, 0, stream>>>(histT, bsums, histTT, NBS);
        partition_kernel<<<PBLK, 1024, 0, stream>>>(src, dst, histTT, packed, ne, NB, chunk);
        agg_lds_kernel<true><<<NB, 1024, 0, stream>>>(histT, packed, bufA, b1, W2, bufB, n, ne, NB);
        agg_lds_kernel<false><<<NB, 1024, 0, stream>>>(histT, packed, bufB, b2, nullptr, bufA, n, ne, NB);
        pool_fc_bf16_kernel<<<NG, 256, 0, stream>>>(bufA, gid, n, Wf1, bf1, Wf2, bf2, out);
    } else {
        // ---------- fallback: fp32 atomic scatter path ----------
        float* bufA = (float*)ws;
        float* bufB = (float*)(ws + featB32);
        float* degF = (float*)(ws + 2 * featB32);

        hipMemsetAsync(bufB, 0, featB32, stream);
        hipMemsetAsync(degF, 0, (size_t)n * 4, stream);

        proj1_f32_kernel<<<4096, 256, 0, stream>>>(h, W1, bufA, n);
        scatter_kernel<true><<<8192, 256, 0, stream>>>(src, dst, bufA, bufB, degF, ne);
        finish1_kernel<<<4096, 256, 0, stream>>>(bufB, degF, bufA, b1, W2, n);
        hipMemsetAsync(bufB, 0, featB32, stream);
        scatter_kernel<false><<<8192, 256, 0, stream>>>(src, dst, bufA, bufB, degF, ne);
        finish2_kernel<<<4096, 256, 0, stream>>>(bufB, degF, bufA, b2, n);
        pool_fc_f32_kernel<<<NG, 256, 0, stream>>>(bufA, gid, n, Wf1, bf1, Wf2, bf2, out);
    }
}

// Round 11
// 1167.016 us; speedup vs baseline: 2.8513x; 2.8513x over previous
//
#include <hip/hip_runtime.h>
#include <hip/hip_bf16.h>

#define IN_FEATS 22
#define HID 16
#define FCH 8
#define NG 256
#define NPB 1024      // nodes per bucket
#define NBLK 256      // hist/scan chunks
#define NBLK_SH 8
#define PBLK 256      // partition blocks (each does NBLK/PBLK chunks)
#define CPB (NBLK / PBLK)

typedef __hip_bfloat16 bf16;

__device__ __forceinline__ void atomAddF(float* p, float v) {
#if defined(__HIP_PLATFORM_AMD__)
    unsafeAtomicAdd(p, v);
#else
    atomicAdd(p, v);
#endif
}

__device__ __forceinline__ float b2f(unsigned short v) {
    union { unsigned u; float f; } t; t.u = ((unsigned)v) << 16; return t.f;
}
__device__ __forceinline__ unsigned short f2b(float f) {
    __hip_bfloat16 h = __float2bfloat16(f);
    return *reinterpret_cast<unsigned short*>(&h);
}

// ---------------- input projection: y1 = h @ W1 (bf16 out) ----------------
__global__ __launch_bounds__(256) void proj1_kernel(
    const float* __restrict__ h, const float* __restrict__ W1,
    bf16* __restrict__ y1, int n) {
    int t = blockIdx.x * blockDim.x + threadIdx.x;
    int total = n * HID;
    int stride = gridDim.x * blockDim.x;
    for (int s = t; s < total; s += stride) {
        int node = s >> 4, f = s & 15;
        const float* hr = h + (long long)node * IN_FEATS;
        float acc = 0.f;
#pragma unroll
        for (int k = 0; k < IN_FEATS; ++k) acc += hr[k] * W1[k * HID + f];
        y1[s] = __float2bfloat16(acc);
    }
}

// ---------------- edge bucketing (radix partition by dst>>10) ----------------
__global__ __launch_bounds__(1024) void hist_kernel(
    const int* __restrict__ dst, int* __restrict__ histT,
    int ne, int NB, int chunk) {
    __shared__ int h[NPB];
    int blk = blockIdx.x, tid = threadIdx.x;
    for (int i = tid; i < NPB; i += 1024) h[i] = 0;
    __syncthreads();
    int s = blk * chunk;
    int e2 = min(s + chunk, ne);
    for (int e = s + tid; e < e2; e += 1024)
        atomicAdd(&h[((unsigned)dst[e]) >> 10], 1);
    __syncthreads();
    for (int b = tid; b < NB; b += 1024) histT[b * NBLK + blk] = h[b];
}

__global__ __launch_bounds__(256) void scan_block_kernel(
    const int* __restrict__ in, int* __restrict__ out,
    int* __restrict__ blockSums, int n) {
    __shared__ int s[256];
    int i = blockIdx.x * 256 + threadIdx.x;
    int v = (i < n) ? in[i] : 0;
    s[threadIdx.x] = v;
    __syncthreads();
    for (int off = 1; off < 256; off <<= 1) {
        int x = (threadIdx.x >= off) ? s[threadIdx.x - off] : 0;
        __syncthreads();
        s[threadIdx.x] += x;
        __syncthreads();
    }
    if (i < n) out[i] = s[threadIdx.x] - v;
    if (threadIdx.x == 255) blockSums[blockIdx.x] = s[255];
}

__global__ __launch_bounds__(1024) void scan_sums_kernel(
    int* __restrict__ blockSums, int nb) {
    __shared__ int s[1024];
    int t = threadIdx.x;
    int loc[4];
    int sum = 0;
#pragma unroll
    for (int k = 0; k < 4; ++k) {
        int idx = t * 4 + k;
        int v = (idx < nb) ? blockSums[idx] : 0;
        loc[k] = sum;
        sum += v;
    }
    s[t] = sum;
    __syncthreads();
    for (int off = 1; off < 1024; off <<= 1) {
        int x = (t >= off) ? s[t - off] : 0;
        __syncthreads();
        s[t] += x;
        __syncthreads();
    }
    int excl = s[t] - sum;
#pragma unroll
    for (int k = 0; k < 4; ++k) {
        int idx = t * 4 + k;
        if (idx < nb) blockSums[idx] = excl + loc[k];
    }
}

__global__ __launch_bounds__(256) void scan_add_kernel(
    int* __restrict__ data, const int* __restrict__ blockSums,
    int* __restrict__ histTT, int total) {
    int i = blockIdx.x * 256 + threadIdx.x;
    if (i < total) {
        int r = data[i] + blockSums[i >> 8];
        data[i] = r;                                         // scanned, bucket-major
        histTT[(i & (NBLK - 1)) * NPB + (i >> NBLK_SH)] = r; // [chunk][bucket]
    }
}

// scatter edges into bucket-grouped 'packed' ((dstLocal<<20)|src).
// 256 blocks x 1 chunk: open-line footprint = 256*NB*64B ~= 16MB (fits L2
// aggregate) so lines are fully written before eviction.
__global__ __launch_bounds__(1024) void partition_kernel(
    const int* __restrict__ src, const int* __restrict__ dst,
    const int* __restrict__ histTT, int* __restrict__ packed,
    int ne, int NB, int chunk) {
    __shared__ int cur[NPB];
    int m = blockIdx.x, tid = threadIdx.x;
    for (int c = m * CPB; c < m * CPB + CPB; ++c) {
        for (int b = tid; b < NB; b += 1024) cur[b] = histTT[c * NPB + b];
        __syncthreads();
        int s = c * chunk, e2 = min(s + chunk, ne);
        for (int e = s + tid; e < e2; e += 1024) {
            int dn = dst[e];
            int bkt = ((unsigned)dn) >> 10;
            int pos = atomicAdd(&cur[bkt], 1);
            packed[pos] = ((dn & (NPB - 1)) << 20) | src[e];
        }
        __syncthreads();
    }
}

// per-bucket counting sort: packed bucket segment -> exact CSR (+ rowoff)
__global__ __launch_bounds__(1024) void csr_build_kernel(
    const int* __restrict__ rowoffE,   // scanned histT (bucket-major)
    const int* __restrict__ packed,
    int* __restrict__ csr, int* __restrict__ rowoff,
    int n, int ne, int NB) {
    __shared__ int h[NPB];
    __shared__ int cur[NPB];
    int b = blockIdx.x, tid = threadIdx.x;
    int start = rowoffE[b << NBLK_SH];
    int end = (b + 1 < NB) ? rowoffE[(b + 1) << NBLK_SH] : ne;
    for (int i = tid; i < NPB; i += 1024) h[i] = 0;
    __syncthreads();
    for (int e = start + tid; e < end; e += 1024)
        atomicAdd(&h[((unsigned)packed[e]) >> 20], 1);
    __syncthreads();
    for (int d = 1; d < NPB; d <<= 1) {
        int idx = (tid + 1) * (d << 1) - 1;
        if (idx < NPB) h[idx] += h[idx - d];
        __syncthreads();
    }
    if (tid == 0) h[NPB - 1] = 0;
    __syncthreads();
    for (int d = NPB >> 1; d >= 1; d >>= 1) {
        int idx = (tid + 1) * (d << 1) - 1;
        if (idx < NPB) { int t = h[idx - d]; h[idx - d] = h[idx]; h[idx] += t; }
        __syncthreads();
    }
    int nodeBase = b << 10;
    int cnt = min(NPB, n - nodeBase);
    for (int li = tid; li < NPB; li += 1024) {
        cur[li] = h[li];
        if (li < cnt) rowoff[nodeBase + li] = start + h[li];
    }
    if (b == NB - 1 && tid == 0) rowoff[n] = ne;
    __syncthreads();
    for (int e = start + tid; e < end; e += 1024) {
        int pk = packed[e];
        int dl = ((unsigned)pk) >> 20;
        int pos = start + atomicAdd(&cur[dl], 1);
        csr[pos] = pk & 0xFFFFF;
    }
}

// gather-mean + bias + relu (+ fused 16x16 @W for layer 1); bf16 features.
// 4 lanes per node; 8 edges in flight per lane-quad; persistent grid.
template <bool PROJ>
__global__ __launch_bounds__(256) void agg_kernel(
    const int* __restrict__ rowoff, const int* __restrict__ csr,
    const bf16* __restrict__ y, const float* __restrict__ bias,
    const float* __restrict__ W, bf16* __restrict__ out, int n) {
    __shared__ float wlds[256];
    if (PROJ) { wlds[threadIdx.x] = W[threadIdx.x]; __syncthreads(); }
    int n4 = n * 4;
    int ntile = (n4 + 255) >> 8;
    for (int t = blockIdx.x; t < ntile; t += gridDim.x) {
        int slot = (t << 8) + threadIdx.x;
        if (slot >= n4) continue;
        int node = slot >> 2, c = slot & 3;
        int lo = rowoff[node], hi = rowoff[node + 1];
        int d = hi - lo;
        float a0 = 0.f, a1 = 0.f, a2 = 0.f, a3 = 0.f;
        int j0 = lo;
        for (; j0 + 8 <= hi; j0 += 8) {
            int m0 = csr[j0 + c];
            int m1 = csr[j0 + 4 + c];
#pragma unroll
            for (int k = 0; k < 4; ++k) {
                int sA = __shfl(m0, k, 4);
                int sB = __shfl(m1, k, 4);
                ushort4 uA = *(const ushort4*)(y + (sA << 4) + (c << 2));
                ushort4 uB = *(const ushort4*)(y + (sB << 4) + (c << 2));
                a0 += b2f(uA.x) + b2f(uB.x);
                a1 += b2f(uA.y) + b2f(uB.y);
                a2 += b2f(uA.z) + b2f(uB.z);
                a3 += b2f(uA.w) + b2f(uB.w);
            }
        }
        if (j0 + 4 <= hi) {
            int myv = csr[j0 + c];
#pragma unroll
            for (int k = 0; k < 4; ++k) {
                int sn = __shfl(myv, k, 4);
                ushort4 u = *(const ushort4*)(y + (sn << 4) + (c << 2));
                a0 += b2f(u.x); a1 += b2f(u.y); a2 += b2f(u.z); a3 += b2f(u.w);
            }
            j0 += 4;
        }
        if (j0 < hi) {
            int rem = hi - j0;
            int myv = (c < rem) ? csr[j0 + c] : 0;
#pragma unroll
            for (int k = 0; k < 4; ++k) {
                int sn = __shfl(myv, k, 4);
                if (k < rem) {
                    ushort4 u = *(const ushort4*)(y + (sn << 4) + (c << 2));
                    a0 += b2f(u.x); a1 += b2f(u.y); a2 += b2f(u.z); a3 += b2f(u.w);
                }
            }
        }
        float x[4];
        if (d > 0) {
            float inv = 1.f / (float)d;
            x[0] = a0 * inv; x[1] = a1 * inv; x[2] = a2 * inv; x[3] = a3 * inv;
        } else {
            ushort4 u = *(const ushort4*)(y + (node << 4) + (c << 2));
            x[0] = b2f(u.x); x[1] = b2f(u.y); x[2] = b2f(u.z); x[3] = b2f(u.w);
        }
#pragma unroll
        for (int f = 0; f < 4; ++f)
            x[f] = fmaxf(x[f] + bias[(c << 2) + f], 0.f);
        ushort4 st;
        if (PROJ) {
            float o[4] = {0.f, 0.f, 0.f, 0.f};
#pragma unroll
            for (int q = 0; q < 4; ++q) {
#pragma unroll
                for (int i = 0; i < 4; ++i) {
                    float xv = __shfl(x[i], q, 4);       // k = q*4 + i
#pragma unroll
                    for (int f = 0; f < 4; ++f)
                        o[f] += xv * wlds[(q * 4 + i) * HID + (c << 2) + f];
                }
            }
            st.x = f2b(o[0]); st.y = f2b(o[1]); st.z = f2b(o[2]); st.w = f2b(o[3]);
        } else {
            st.x = f2b(x[0]); st.y = f2b(x[1]); st.z = f2b(x[2]); st.w = f2b(x[3]);
        }
        *(ushort4*)(out + (node << 4) + (c << 2)) = st;
    }
}

// ---------------- pooling + FC head (bf16 features in) ----------------
__global__ __launch_bounds__(256) void pool_fc_bf16_kernel(
    const bf16* __restrict__ x2, const int* __restrict__ gid, int n,
    const float* __restrict__ Wf1, const float* __restrict__ bf1,
    const float* __restrict__ Wf2, const float* __restrict__ bf2,
    float* __restrict__ out) {
    int g = blockIdx.x;
    int lo, hi;
    {
        int a = 0, b = n;
        while (a < b) { int m = (a + b) >> 1; if (gid[m] < g) a = m + 1; else b = m; }
        lo = a;
        b = n;
        while (a < b) { int m = (a + b) >> 1; if (gid[m] < g + 1) a = m + 1; else b = m; }
        hi = a;
    }
    int cnt = hi - lo;
    float acc[HID];
#pragma unroll
    for (int k = 0; k < HID; ++k) acc[k] = 0.f;
    for (int i = lo + threadIdx.x; i < hi; i += blockDim.x) {
        const uint4* p = (const uint4*)(x2 + (long long)i * HID);
#pragma unroll
        for (int q = 0; q < 2; ++q) {
            uint4 u = p[q];
            unsigned w[4] = {u.x, u.y, u.z, u.w};
#pragma unroll
            for (int c = 0; c < 4; ++c) {
                union { unsigned i; float f; } loV, hiV;
                loV.i = (w[c] & 0xFFFFu) << 16;
                hiV.i = w[c] & 0xFFFF0000u;
                acc[q * 8 + c * 2 + 0] += loV.f;
                acc[q * 8 + c * 2 + 1] += hiV.f;
            }
        }
    }
    __shared__ float smem[256][HID];
#pragma unroll
    for (int k = 0; k < HID; ++k) smem[threadIdx.x][k] = acc[k];
    __syncthreads();
    for (int off = 128; off > 0; off >>= 1) {
        if (threadIdx.x < off)
            for (int k = 0; k < HID; ++k)
                smem[threadIdx.x][k] += smem[threadIdx.x + off][k];
        __syncthreads();
    }
    if (threadIdx.x == 0) {
        float inv = cnt > 0 ? 1.f / (float)cnt : 0.f;
        float hg[HID];
        for (int k = 0; k < HID; ++k) hg[k] = smem[0][k] * inv;
        float f1[FCH];
        for (int j = 0; j < FCH; ++j) {
            float a = bf1[j];
            for (int k = 0; k < HID; ++k) a += hg[k] * Wf1[k * FCH + j];
            f1[j] = a;
        }
        float o = bf2[0];
        for (int j = 0; j < FCH; ++j) o += f1[j] * Wf2[j];
        out[g] = 1.f / (1.f + expf(-o));
    }
}

// ---------------- fallback: atomic-scatter path (fp32, proven R1) ----------
__global__ __launch_bounds__(256) void proj1_f32_kernel(
    const float* __restrict__ h, const float* __restrict__ W1,
    float* __restrict__ y1, int n) {
    int t = blockIdx.x * blockDim.x + threadIdx.x;
    int total = n * HID;
    int stride = gridDim.x * blockDim.x;
    for (int s = t; s < total; s += stride) {
        int node = s >> 4, f = s & 15;
        const float* hr = h + (long long)node * IN_FEATS;
        float acc = 0.f;
#pragma unroll
        for (int k = 0; k < IN_FEATS; ++k) acc += hr[k] * W1[k * HID + f];
        y1[s] = acc;
    }
}

template <bool COUNT_DEG>
__global__ __launch_bounds__(256) void scatter_kernel(
    const int* __restrict__ src, const int* __restrict__ dst,
    const float* __restrict__ y, float* __restrict__ agg,
    float* __restrict__ deg, int n_edges) {
    int t = blockIdx.x * blockDim.x + threadIdx.x;
    int total = n_edges * HID;
    int stride = gridDim.x * blockDim.x;
    for (int s = t; s < total; s += stride) {
        int e = s >> 4, f = s & 15;
        int sn = src[e], dn = dst[e];
        float v = y[(long long)sn * HID + f];
        atomAddF(&agg[(long long)dn * HID + f], v);
        if (COUNT_DEG && f == 0) atomAddF(&deg[dn], 1.0f);
    }
}

__global__ __launch_bounds__(256) void finish1_kernel(
    const float* __restrict__ agg, const float* __restrict__ deg,
    float* __restrict__ y, const float* __restrict__ b1,
    const float* __restrict__ W2, int n) {
    int i = blockIdx.x * blockDim.x + threadIdx.x;
    int stride = gridDim.x * blockDim.x;
    for (; i < n; i += stride) {
        float d = deg[i];
        float inv = d > 0.f ? 1.f / d : 0.f;
        bool mail = d > 0.f;
        const float4* ag = (const float4*)(agg + (long long)i * HID);
        const float4* yy = (const float4*)(y + (long long)i * HID);
        float x1[HID];
#pragma unroll
        for (int q = 0; q < 4; ++q) {
            float4 a = ag[q];
            float4 b = yy[q];
            float v0 = mail ? a.x * inv : b.x;
            float v1 = mail ? a.y * inv : b.y;
            float v2 = mail ? a.z * inv : b.z;
            float v3 = mail ? a.w * inv : b.w;
            x1[q * 4 + 0] = fmaxf(v0 + b1[q * 4 + 0], 0.f);
            x1[q * 4 + 1] = fmaxf(v1 + b1[q * 4 + 1], 0.f);
            x1[q * 4 + 2] = fmaxf(v2 + b1[q * 4 + 2], 0.f);
            x1[q * 4 + 3] = fmaxf(v3 + b1[q * 4 + 3], 0.f);
        }
        float out[HID];
#pragma unroll
        for (int f = 0; f < HID; ++f) out[f] = 0.f;
#pragma unroll
        for (int k = 0; k < HID; ++k) {
            float xv = x1[k];
#pragma unroll
            for (int f = 0; f < HID; ++f) out[f] += xv * W2[k * HID + f];
        }
        float4* dst4 = (float4*)(y + (long long)i * HID);
#pragma unroll
        for (int q = 0; q < 4; ++q)
            dst4[q] = make_float4(out[q * 4 + 0], out[q * 4 + 1],
                                  out[q * 4 + 2], out[q * 4 + 3]);
    }
}

__global__ __launch_bounds__(256) void finish2_kernel(
    const float* __restrict__ agg, const float* __restrict__ deg,
    float* __restrict__ y, const float* __restrict__ b2, int n) {
    int i = blockIdx.x * blockDim.x + threadIdx.x;
    int stride = gridDim.x * blockDim.x;
    for (; i < n; i += stride) {
        float d = deg[i];
        float inv = d > 0.f ? 1.f / d : 0.f;
        bool mail = d > 0.f;
        const float4* ag = (const float4*)(agg + (long long)i * HID);
        float4* yy = (float4*)(y + (long long)i * HID);
#pragma unroll
        for (int q = 0; q < 4; ++q) {
            float4 a = ag[q];
            float4 b = yy[q];
            float v0 = mail ? a.x * inv : b.x;
            float v1 = mail ? a.y * inv : b.y;
            float v2 = mail ? a.z * inv : b.z;
            float v3 = mail ? a.w * inv : b.w;
            yy[q] = make_float4(fmaxf(v0 + b2[q * 4 + 0], 0.f),
                                fmaxf(v1 + b2[q * 4 + 1], 0.f),
                                fmaxf(v2 + b2[q * 4 + 2], 0.f),
                                fmaxf(v3 + b2[q * 4 + 3], 0.f));
        }
    }
}

__global__ __launch_bounds__(256) void pool_fc_f32_kernel(
    const float* __restrict__ x2, const int* __restrict__ gid, int n,
    const float* __restrict__ Wf1, const float* __restrict__ bf1,
    const float* __restrict__ Wf2, const float* __restrict__ bf2,
    float* __restrict__ out) {
    int g = blockIdx.x;
    int lo, hi;
    {
        int a = 0, b = n;
        while (a < b) { int m = (a + b) >> 1; if (gid[m] < g) a = m + 1; else b = m; }
        lo = a;
        b = n;
        while (a < b) { int m = (a + b) >> 1; if (gid[m] < g + 1) a = m + 1; else b = m; }
        hi = a;
    }
    int cnt = hi - lo;
    float acc[HID];
#pragma unroll
    for (int k = 0; k < HID; ++k) acc[k] = 0.f;
    for (int i = lo + threadIdx.x; i < hi; i += blockDim.x) {
        const float4* p = (const float4*)(x2 + (long long)i * HID);
#pragma unroll
        for (int q = 0; q < 4; ++q) {
            float4 v = p[q];
            acc[q * 4 + 0] += v.x; acc[q * 4 + 1] += v.y;
            acc[q * 4 + 2] += v.z; acc[q * 4 + 3] += v.w;
        }
    }
    __shared__ float smem[256][HID];
#pragma unroll
    for (int k = 0; k < HID; ++k) smem[threadIdx.x][k] = acc[k];
    __syncthreads();
    for (int off = 128; off > 0; off >>= 1) {
        if (threadIdx.x < off)
            for (int k = 0; k < HID; ++k)
                smem[threadIdx.x][k] += smem[threadIdx.x + off][k];
        __syncthreads();
    }
    if (threadIdx.x == 0) {
        float inv = cnt > 0 ? 1.f / (float)cnt : 0.f;
        float hg[HID];
        for (int k = 0; k < HID; ++k) hg[k] = smem[0][k] * inv;
        float f1[FCH];
        for (int j = 0; j < FCH; ++j) {
            float a = bf1[j];
            for (int k = 0; k < HID; ++k) a += hg[k] * Wf1[k * FCH + j];
            f1[j] = a;
        }
        float o = bf2[0];
        for (int j = 0; j < FCH; ++j) o += f1[j] * Wf2[j];
        out[g] = 1.f / (1.f + expf(-o));
    }
}

extern "C" void kernel_launch(void* const* d_in, const int* in_sizes, int n_in,
                              void* d_out, int out_size, void* d_ws, size_t ws_size,
                              hipStream_t stream) {
    const float* h   = (const float*)d_in[0];
    const int*   src = (const int*)d_in[1];
    const int*   dst = (const int*)d_in[2];
    const int*   gid = (const int*)d_in[3];
    const float* W1  = (const float*)d_in[4];
    const float* b1  = (const float*)d_in[5];
    const float* W2  = (const float*)d_in[6];
    const float* b2  = (const float*)d_in[7];
    const float* Wf1 = (const float*)d_in[8];
    const float* bf1 = (const float*)d_in[9];
    const float* Wf2 = (const float*)d_in[10];
    const float* bf2 = (const float*)d_in[11];
    float* out = (float*)d_out;

    int n  = in_sizes[3];
    int ne = in_sizes[1];

    size_t featB16 = (size_t)n * HID * 2;        // 32 MB (bf16 features)
    size_t featB32 = (size_t)n * HID * 4;        // 64 MB (fallback)
    size_t edgeB   = (size_t)ne * 4;             // 64 MB
    size_t slot2   = featB16 > edgeB ? featB16 : edgeB;  // bufB / packed alias
    int NB  = (n + NPB - 1) / NPB;
    int NBS = NB * NBLK;
    int nbS = (NBS + 255) / 256;

    size_t off_bufA   = 0;
    size_t off_slot2  = off_bufA + featB16;
    size_t off_csr    = off_slot2 + slot2;
    size_t off_histT  = off_csr + edgeB;
    size_t off_histTT = off_histT + (size_t)NBS * 4;
    size_t off_rowoff = off_histTT + (size_t)NPB * NBLK * 4;
    size_t off_bsums  = off_rowoff + (size_t)(n + 1) * 4;
    size_t need       = off_bsums + 4096 * 4;

    char* ws = (char*)d_ws;
    if (ws_size >= need && n <= (1 << 20) && NB <= NPB && nbS <= 4096) {
        // ---------- radix-CSR + bf16 gather path (best known structure) ----
        bf16*  bufA   = (bf16*)(ws + off_bufA);
        bf16*  bufB   = (bf16*)(ws + off_slot2);
        int*   packed = (int*) (ws + off_slot2);   // alias: dead before agg1
        int*   csr    = (int*) (ws + off_csr);
        int*   histT  = (int*) (ws + off_histT);
        int*   histTT = (int*) (ws + off_histTT);
        int*   rowoff = (int*) (ws + off_rowoff);
        int*   bsums  = (int*) (ws + off_bsums);

        int chunk = (ne + NBLK - 1) / NBLK;
        int ntile = (n * 4 + 255) / 256;
        int aggGrid = ntile < 2048 ? ntile : 2048;

        proj1_kernel<<<4096, 256, 0, stream>>>(h, W1, bufA, n);
        hist_kernel<<<NBLK, 1024, 0, stream>>>(dst, histT, ne, NB, chunk);
        scan_block_kernel<<<nbS, 256, 0, stream>>>(histT, histT, bsums, NBS);
        scan_sums_kernel<<<1, 1024, 0, stream>>>(bsums, nbS);
        scan_add_kernel<<<nbS, 256, 0, stream>>>(histT, bsums, histTT, NBS);
        partition_kernel<<<PBLK, 1024, 0, stream>>>(src, dst, histTT, packed, ne, NB, chunk);
        csr_build_kernel<<<NB, 1024, 0, stream>>>(histT, packed, csr, rowoff, n, ne, NB);
        agg_kernel<true><<<aggGrid, 256, 0, stream>>>(rowoff, csr, bufA, b1, W2, bufB, n);
        agg_kernel<false><<<aggGrid, 256, 0, stream>>>(rowoff, csr, bufB, b2, nullptr, bufA, n);
        pool_fc_bf16_kernel<<<NG, 256, 0, stream>>>(bufA, gid, n, Wf1, bf1, Wf2, bf2, out);
    } else {
        // ---------- fallback: fp32 atomic scatter path ----------
        float* bufA = (float*)ws;
        float* bufB = (float*)(ws + featB32);
        float* degF = (float*)(ws + 2 * featB32);

        hipMemsetAsync(bufB, 0, featB32, stream);
        hipMemsetAsync(degF, 0, (size_t)n * 4, stream);

        proj1_f32_kernel<<<4096, 256, 0, stream>>>(h, W1, bufA, n);
        scatter_kernel<true><<<8192, 256, 0, stream>>>(src, dst, bufA, bufB, degF, ne);
        finish1_kernel<<<4096, 256, 0, stream>>>(bufB, degF, bufA, b1, W2, n);
        hipMemsetAsync(bufB, 0, featB32, stream);
        scatter_kernel<false><<<8192, 256, 0, stream>>>(src, dst, bufA, bufB, degF, ne);
        finish2_kernel<<<4096, 256, 0, stream>>>(bufB, degF, bufA, b2, n);
        pool_fc_f32_kernel<<<NG, 256, 0, stream>>>(bufA, gid, n, Wf1, bf1, Wf2, bf2, out);
    }
}

// Round 12
// 1029.278 us; speedup vs baseline: 3.2328x; 1.1338x over previous
//
#include <hip/hip_runtime.h>
#include <hip/hip_bf16.h>

#define IN_FEATS 22
#define HID 16
#define FCH 8
#define NG 256
#define NPB 1024      // nodes per bucket
#define NBLK 256      // hist/scan chunks
#define NBLK_SH 8
#define PBLK 256      // partition blocks (each does NBLK/PBLK chunks)
#define CPB (NBLK / PBLK)
#define EDGE_CACHE 18432   // 72 KB LDS edge cache (max bucket ~16.9K edges)

typedef __hip_bfloat16 bf16;

__device__ __forceinline__ void atomAddF(float* p, float v) {
#if defined(__HIP_PLATFORM_AMD__)
    unsafeAtomicAdd(p, v);
#else
    atomicAdd(p, v);
#endif
}

__device__ __forceinline__ float b2f(unsigned short v) {
    union { unsigned u; float f; } t; t.u = ((unsigned)v) << 16; return t.f;
}
__device__ __forceinline__ unsigned short f2b(float f) {
    __hip_bfloat16 h = __float2bfloat16(f);
    return *reinterpret_cast<unsigned short*>(&h);
}

// ---------------- input projection: y1 = h @ W1 (bf16 out) ----------------
// one thread per node: 22-float row read once, 16 outputs, W1 in LDS.
__global__ __launch_bounds__(256) void proj1_kernel(
    const float* __restrict__ h, const float* __restrict__ W1,
    bf16* __restrict__ y1, int n) {
    __shared__ float w[IN_FEATS * HID];
    for (int i = threadIdx.x; i < IN_FEATS * HID; i += 256) w[i] = W1[i];
    __syncthreads();
    int node = blockIdx.x * blockDim.x + threadIdx.x;
    if (node >= n) return;
    const float* hr = h + (long long)node * IN_FEATS;
    float acc[HID];
#pragma unroll
    for (int f = 0; f < HID; ++f) acc[f] = 0.f;
#pragma unroll
    for (int k = 0; k < IN_FEATS; ++k) {
        float hv = hr[k];
#pragma unroll
        for (int f = 0; f < HID; ++f) acc[f] += hv * w[k * HID + f];
    }
    ushort4* op = (ushort4*)(y1 + ((long long)node << 4));
#pragma unroll
    for (int q = 0; q < 4; ++q) {
        ushort4 st;
        st.x = f2b(acc[q * 4 + 0]); st.y = f2b(acc[q * 4 + 1]);
        st.z = f2b(acc[q * 4 + 2]); st.w = f2b(acc[q * 4 + 3]);
        op[q] = st;
    }
}

// ---------------- edge bucketing (radix partition by dst>>10) ----------------
__global__ __launch_bounds__(1024) void hist_kernel(
    const int* __restrict__ dst, int* __restrict__ histT,
    int ne, int NB, int chunk) {
    __shared__ int h[NPB];
    int blk = blockIdx.x, tid = threadIdx.x;
    for (int i = tid; i < NPB; i += 1024) h[i] = 0;
    __syncthreads();
    int s = blk * chunk;
    int e2 = min(s + chunk, ne);
    for (int e = s + tid; e < e2; e += 1024)
        atomicAdd(&h[((unsigned)dst[e]) >> 10], 1);
    __syncthreads();
    for (int b = tid; b < NB; b += 1024) histT[b * NBLK + blk] = h[b];
}

__global__ __launch_bounds__(256) void scan_block_kernel(
    const int* __restrict__ in, int* __restrict__ out,
    int* __restrict__ blockSums, int n) {
    __shared__ int s[256];
    int i = blockIdx.x * 256 + threadIdx.x;
    int v = (i < n) ? in[i] : 0;
    s[threadIdx.x] = v;
    __syncthreads();
    for (int off = 1; off < 256; off <<= 1) {
        int x = (threadIdx.x >= off) ? s[threadIdx.x - off] : 0;
        __syncthreads();
        s[threadIdx.x] += x;
        __syncthreads();
    }
    if (i < n) out[i] = s[threadIdx.x] - v;
    if (threadIdx.x == 255) blockSums[blockIdx.x] = s[255];
}

__global__ __launch_bounds__(1024) void scan_sums_kernel(
    int* __restrict__ blockSums, int nb) {
    __shared__ int s[1024];
    int t = threadIdx.x;
    int loc[4];
    int sum = 0;
#pragma unroll
    for (int k = 0; k < 4; ++k) {
        int idx = t * 4 + k;
        int v = (idx < nb) ? blockSums[idx] : 0;
        loc[k] = sum;
        sum += v;
    }
    s[t] = sum;
    __syncthreads();
    for (int off = 1; off < 1024; off <<= 1) {
        int x = (t >= off) ? s[t - off] : 0;
        __syncthreads();
        s[t] += x;
        __syncthreads();
    }
    int excl = s[t] - sum;
#pragma unroll
    for (int k = 0; k < 4; ++k) {
        int idx = t * 4 + k;
        if (idx < nb) blockSums[idx] = excl + loc[k];
    }
}

__global__ __launch_bounds__(256) void scan_add_kernel(
    int* __restrict__ data, const int* __restrict__ blockSums,
    int* __restrict__ histTT, int total) {
    int i = blockIdx.x * 256 + threadIdx.x;
    if (i < total) {
        int r = data[i] + blockSums[i >> 8];
        data[i] = r;                                         // scanned, bucket-major
        histTT[(i & (NBLK - 1)) * NPB + (i >> NBLK_SH)] = r; // [chunk][bucket]
    }
}

// scatter edges into bucket-grouped 'packed' ((dstLocal<<20)|src).
// 256 blocks: open-line footprint = 256*NB*64B ~= 16MB (fits L2 aggregate)
// so lines are fully written before eviction.
__global__ __launch_bounds__(1024) void partition_kernel(
    const int* __restrict__ src, const int* __restrict__ dst,
    const int* __restrict__ histTT, int* __restrict__ packed,
    int ne, int NB, int chunk) {
    __shared__ int cur[NPB];
    int m = blockIdx.x, tid = threadIdx.x;
    for (int c = m * CPB; c < m * CPB + CPB; ++c) {
        for (int b = tid; b < NB; b += 1024) cur[b] = histTT[c * NPB + b];
        __syncthreads();
        int s = c * chunk, e2 = min(s + chunk, ne);
        for (int e = s + tid; e < e2; e += 1024) {
            int dn = dst[e];
            int bkt = ((unsigned)dn) >> 10;
            int pos = atomicAdd(&cur[bkt], 1);
            packed[pos] = ((dn & (NPB - 1)) << 20) | src[e];
        }
        __syncthreads();
    }
}

// per-bucket counting sort: packed bucket segment -> exact CSR (+ rowoff).
// Bucket's edges cached in LDS (single global read); fallback to global
// re-read for oversized buckets (>EDGE_CACHE).
__global__ __launch_bounds__(1024) void csr_build_kernel(
    const int* __restrict__ rowoffE,   // scanned histT (bucket-major)
    const int* __restrict__ packed,
    int* __restrict__ csr, int* __restrict__ rowoff,
    int n, int ne, int NB) {
    __shared__ int h[NPB];
    __shared__ int cur[NPB];
    __shared__ int ecache[EDGE_CACHE];
    int b = blockIdx.x, tid = threadIdx.x;
    int start = rowoffE[b << NBLK_SH];
    int end = (b + 1 < NB) ? rowoffE[(b + 1) << NBLK_SH] : ne;
    int len = end - start;
    bool cached = (len <= EDGE_CACHE);
    if (cached)
        for (int i = tid; i < len; i += 1024) ecache[i] = packed[start + i];
    for (int i = tid; i < NPB; i += 1024) h[i] = 0;
    __syncthreads();
    if (cached) {
        for (int i = tid; i < len; i += 1024)
            atomicAdd(&h[((unsigned)ecache[i]) >> 20], 1);
    } else {
        for (int e = start + tid; e < end; e += 1024)
            atomicAdd(&h[((unsigned)packed[e]) >> 20], 1);
    }
    __syncthreads();
    for (int d = 1; d < NPB; d <<= 1) {
        int idx = (tid + 1) * (d << 1) - 1;
        if (idx < NPB) h[idx] += h[idx - d];
        __syncthreads();
    }
    if (tid == 0) h[NPB - 1] = 0;
    __syncthreads();
    for (int d = NPB >> 1; d >= 1; d >>= 1) {
        int idx = (tid + 1) * (d << 1) - 1;
        if (idx < NPB) { int t = h[idx - d]; h[idx - d] = h[idx]; h[idx] += t; }
        __syncthreads();
    }
    int nodeBase = b << 10;
    int cnt = min(NPB, n - nodeBase);
    for (int li = tid; li < NPB; li += 1024) {
        cur[li] = h[li];
        if (li < cnt) rowoff[nodeBase + li] = start + h[li];
    }
    if (b == NB - 1 && tid == 0) rowoff[n] = ne;
    __syncthreads();
    if (cached) {
        for (int i = tid; i < len; i += 1024) {
            int pk = ecache[i];
            int dl = ((unsigned)pk) >> 20;
            int pos = start + atomicAdd(&cur[dl], 1);
            csr[pos] = pk & 0xFFFFF;
        }
    } else {
        for (int e = start + tid; e < end; e += 1024) {
            int pk = packed[e];
            int dl = ((unsigned)pk) >> 20;
            int pos = start + atomicAdd(&cur[dl], 1);
            csr[pos] = pk & 0xFFFFF;
        }
    }
}

// gather-mean + bias + relu (+ fused 16x16 @W for layer 1); bf16 features.
// 4 lanes per node; 8 edges in flight per lane-quad; persistent grid.
template <bool PROJ>
__global__ __launch_bounds__(256) void agg_kernel(
    const int* __restrict__ rowoff, const int* __restrict__ csr,
    const bf16* __restrict__ y, const float* __restrict__ bias,
    const float* __restrict__ W, bf16* __restrict__ out, int n) {
    __shared__ float wlds[256];
    if (PROJ) { wlds[threadIdx.x] = W[threadIdx.x]; __syncthreads(); }
    int n4 = n * 4;
    int ntile = (n4 + 255) >> 8;
    for (int t = blockIdx.x; t < ntile; t += gridDim.x) {
        int slot = (t << 8) + threadIdx.x;
        if (slot >= n4) continue;
        int node = slot >> 2, c = slot & 3;
        int lo = rowoff[node], hi = rowoff[node + 1];
        int d = hi - lo;
        float a0 = 0.f, a1 = 0.f, a2 = 0.f, a3 = 0.f;
        int j0 = lo;
        for (; j0 + 8 <= hi; j0 += 8) {
            int m0 = csr[j0 + c];
            int m1 = csr[j0 + 4 + c];
#pragma unroll
            for (int k = 0; k < 4; ++k) {
                int sA = __shfl(m0, k, 4);
                int sB = __shfl(m1, k, 4);
                ushort4 uA = *(const ushort4*)(y + (sA << 4) + (c << 2));
                ushort4 uB = *(const ushort4*)(y + (sB << 4) + (c << 2));
                a0 += b2f(uA.x) + b2f(uB.x);
                a1 += b2f(uA.y) + b2f(uB.y);
                a2 += b2f(uA.z) + b2f(uB.z);
                a3 += b2f(uA.w) + b2f(uB.w);
            }
        }
        if (j0 + 4 <= hi) {
            int myv = csr[j0 + c];
#pragma unroll
            for (int k = 0; k < 4; ++k) {
                int sn = __shfl(myv, k, 4);
                ushort4 u = *(const ushort4*)(y + (sn << 4) + (c << 2));
                a0 += b2f(u.x); a1 += b2f(u.y); a2 += b2f(u.z); a3 += b2f(u.w);
            }
            j0 += 4;
        }
        if (j0 < hi) {
            int rem = hi - j0;
            int myv = (c < rem) ? csr[j0 + c] : 0;
#pragma unroll
            for (int k = 0; k < 4; ++k) {
                int sn = __shfl(myv, k, 4);
                if (k < rem) {
                    ushort4 u = *(const ushort4*)(y + (sn << 4) + (c << 2));
                    a0 += b2f(u.x); a1 += b2f(u.y); a2 += b2f(u.z); a3 += b2f(u.w);
                }
            }
        }
        float x[4];
        if (d > 0) {
            float inv = 1.f / (float)d;
            x[0] = a0 * inv; x[1] = a1 * inv; x[2] = a2 * inv; x[3] = a3 * inv;
        } else {
            ushort4 u = *(const ushort4*)(y + (node << 4) + (c << 2));
            x[0] = b2f(u.x); x[1] = b2f(u.y); x[2] = b2f(u.z); x[3] = b2f(u.w);
        }
#pragma unroll
        for (int f = 0; f < 4; ++f)
            x[f] = fmaxf(x[f] + bias[(c << 2) + f], 0.f);
        ushort4 st;
        if (PROJ) {
            float o[4] = {0.f, 0.f, 0.f, 0.f};
#pragma unroll
            for (int q = 0; q < 4; ++q) {
#pragma unroll
                for (int i = 0; i < 4; ++i) {
                    float xv = __shfl(x[i], q, 4);       // k = q*4 + i
#pragma unroll
                    for (int f = 0; f < 4; ++f)
                        o[f] += xv * wlds[(q * 4 + i) * HID + (c << 2) + f];
                }
            }
            st.x = f2b(o[0]); st.y = f2b(o[1]); st.z = f2b(o[2]); st.w = f2b(o[3]);
        } else {
            st.x = f2b(x[0]); st.y = f2b(x[1]); st.z = f2b(x[2]); st.w = f2b(x[3]);
        }
        *(ushort4*)(out + (node << 4) + (c << 2)) = st;
    }
}

// ---------------- pooling + FC head (bf16 features in) ----------------
__global__ __launch_bounds__(256) void pool_fc_bf16_kernel(
    const bf16* __restrict__ x2, const int* __restrict__ gid, int n,
    const float* __restrict__ Wf1, const float* __restrict__ bf1,
    const float* __restrict__ Wf2, const float* __restrict__ bf2,
    float* __restrict__ out) {
    int g = blockIdx.x;
    int lo, hi;
    {
        int a = 0, b = n;
        while (a < b) { int m = (a + b) >> 1; if (gid[m] < g) a = m + 1; else b = m; }
        lo = a;
        b = n;
        while (a < b) { int m = (a + b) >> 1; if (gid[m] < g + 1) a = m + 1; else b = m; }
        hi = a;
    }
    int cnt = hi - lo;
    float acc[HID];
#pragma unroll
    for (int k = 0; k < HID; ++k) acc[k] = 0.f;
    for (int i = lo + threadIdx.x; i < hi; i += blockDim.x) {
        const uint4* p = (const uint4*)(x2 + (long long)i * HID);
#pragma unroll
        for (int q = 0; q < 2; ++q) {
            uint4 u = p[q];
            unsigned w[4] = {u.x, u.y, u.z, u.w};
#pragma unroll
            for (int c = 0; c < 4; ++c) {
                union { unsigned i; float f; } loV, hiV;
                loV.i = (w[c] & 0xFFFFu) << 16;
                hiV.i = w[c] & 0xFFFF0000u;
                acc[q * 8 + c * 2 + 0] += loV.f;
                acc[q * 8 + c * 2 + 1] += hiV.f;
            }
        }
    }
    __shared__ float smem[256][HID];
#pragma unroll
    for (int k = 0; k < HID; ++k) smem[threadIdx.x][k] = acc[k];
    __syncthreads();
    for (int off = 128; off > 0; off >>= 1) {
        if (threadIdx.x < off)
            for (int k = 0; k < HID; ++k)
                smem[threadIdx.x][k] += smem[threadIdx.x + off][k];
        __syncthreads();
    }
    if (threadIdx.x == 0) {
        float inv = cnt > 0 ? 1.f / (float)cnt : 0.f;
        float hg[HID];
        for (int k = 0; k < HID; ++k) hg[k] = smem[0][k] * inv;
        float f1[FCH];
        for (int j = 0; j < FCH; ++j) {
            float a = bf1[j];
            for (int k = 0; k < HID; ++k) a += hg[k] * Wf1[k * FCH + j];
            f1[j] = a;
        }
        float o = bf2[0];
        for (int j = 0; j < FCH; ++j) o += f1[j] * Wf2[j];
        out[g] = 1.f / (1.f + expf(-o));
    }
}

// ---------------- fallback: atomic-scatter path (fp32, proven R1) ----------
__global__ __launch_bounds__(256) void proj1_f32_kernel(
    const float* __restrict__ h, const float* __restrict__ W1,
    float* __restrict__ y1, int n) {
    int t = blockIdx.x * blockDim.x + threadIdx.x;
    int total = n * HID;
    int stride = gridDim.x * blockDim.x;
    for (int s = t; s < total; s += stride) {
        int node = s >> 4, f = s & 15;
        const float* hr = h + (long long)node * IN_FEATS;
        float acc = 0.f;
#pragma unroll
        for (int k = 0; k < IN_FEATS; ++k) acc += hr[k] * W1[k * HID + f];
        y1[s] = acc;
    }
}

template <bool COUNT_DEG>
__global__ __launch_bounds__(256) void scatter_kernel(
    const int* __restrict__ src, const int* __restrict__ dst,
    const float* __restrict__ y, float* __restrict__ agg,
    float* __restrict__ deg, int n_edges) {
    int t = blockIdx.x * blockDim.x + threadIdx.x;
    int total = n_edges * HID;
    int stride = gridDim.x * blockDim.x;
    for (int s = t; s < total; s += stride) {
        int e = s >> 4, f = s & 15;
        int sn = src[e], dn = dst[e];
        float v = y[(long long)sn * HID + f];
        atomAddF(&agg[(long long)dn * HID + f], v);
        if (COUNT_DEG && f == 0) atomAddF(&deg[dn], 1.0f);
    }
}

__global__ __launch_bounds__(256) void finish1_kernel(
    const float* __restrict__ agg, const float* __restrict__ deg,
    float* __restrict__ y, const float* __restrict__ b1,
    const float* __restrict__ W2, int n) {
    int i = blockIdx.x * blockDim.x + threadIdx.x;
    int stride = gridDim.x * blockDim.x;
    for (; i < n; i += stride) {
        float d = deg[i];
        float inv = d > 0.f ? 1.f / d : 0.f;
        bool mail = d > 0.f;
        const float4* ag = (const float4*)(agg + (long long)i * HID);
        const float4* yy = (const float4*)(y + (long long)i * HID);
        float x1[HID];
#pragma unroll
        for (int q = 0; q < 4; ++q) {
            float4 a = ag[q];
            float4 b = yy[q];
            float v0 = mail ? a.x * inv : b.x;
            float v1 = mail ? a.y * inv : b.y;
            float v2 = mail ? a.z * inv : b.z;
            float v3 = mail ? a.w * inv : b.w;
            x1[q * 4 + 0] = fmaxf(v0 + b1[q * 4 + 0], 0.f);
            x1[q * 4 + 1] = fmaxf(v1 + b1[q * 4 + 1], 0.f);
            x1[q * 4 + 2] = fmaxf(v2 + b1[q * 4 + 2], 0.f);
            x1[q * 4 + 3] = fmaxf(v3 + b1[q * 4 + 3], 0.f);
        }
        float out[HID];
#pragma unroll
        for (int f = 0; f < HID; ++f) out[f] = 0.f;
#pragma unroll
        for (int k = 0; k < HID; ++k) {
            float xv = x1[k];
#pragma unroll
            for (int f = 0; f < HID; ++f) out[f] += xv * W2[k * HID + f];
        }
        float4* dst4 = (float4*)(y + (long long)i * HID);
#pragma unroll
        for (int q = 0; q < 4; ++q)
            dst4[q] = make_float4(out[q * 4 + 0], out[q * 4 + 1],
                                  out[q * 4 + 2], out[q * 4 + 3]);
    }
}

__global__ __launch_bounds__(256) void finish2_kernel(
    const float* __restrict__ agg, const float* __restrict__ deg,
    float* __restrict__ y, const float* __restrict__ b2, int n) {
    int i = blockIdx.x * blockDim.x + threadIdx.x;
    int stride = gridDim.x * blockDim.x;
    for (; i < n; i += stride) {
        float d = deg[i];
        float inv = d > 0.f ? 1.f / d : 0.f;
        bool mail = d > 0.f;
        const float4* ag = (const float4*)(agg + (long long)i * HID);
        float4* yy = (float4*)(y + (long long)i * HID);
#pragma unroll
        for (int q = 0; q < 4; ++q) {
            float4 a = ag[q];
            float4 b = yy[q];
            float v0 = mail ? a.x * inv : b.x;
            float v1 = mail ? a.y * inv : b.y;
            float v2 = mail ? a.z * inv : b.z;
            float v3 = mail ? a.w * inv : b.w;
            yy[q] = make_float4(fmaxf(v0 + b2[q * 4 + 0], 0.f),
                                fmaxf(v1 + b2[q * 4 + 1], 0.f),
                                fmaxf(v2 + b2[q * 4 + 2], 0.f),
                                fmaxf(v3 + b2[q * 4 + 3], 0.f));
        }
    }
}

__global__ __launch_bounds__(256) void pool_fc_f32_kernel(
    const float* __restrict__ x2, const int* __restrict__ gid, int n,
    const float* __restrict__ Wf1, const float* __restrict__ bf1,
    const float* __restrict__ Wf2, const float* __restrict__ bf2,
    float* __restrict__ out) {
    int g = blockIdx.x;
    int lo, hi;
    {
        int a = 0, b = n;
        while (a < b) { int m = (a + b) >> 1; if (gid[m] < g) a = m + 1; else b = m; }
        lo = a;
        b = n;
        while (a < b) { int m = (a + b) >> 1; if (gid[m] < g + 1) a = m + 1; else b = m; }
        hi = a;
    }
    int cnt = hi - lo;
    float acc[HID];
#pragma unroll
    for (int k = 0; k < HID; ++k) acc[k] = 0.f;
    for (int i = lo + threadIdx.x; i < hi; i += blockDim.x) {
        const float4* p = (const float4*)(x2 + (long long)i * HID);
#pragma unroll
        for (int q = 0; q < 4; ++q) {
            float4 v = p[q];
            acc[q * 4 + 0] += v.x; acc[q * 4 + 1] += v.y;
            acc[q * 4 + 2] += v.z; acc[q * 4 + 3] += v.w;
        }
    }
    __shared__ float smem[256][HID];
#pragma unroll
    for (int k = 0; k < HID; ++k) smem[threadIdx.x][k] = acc[k];
    __syncthreads();
    for (int off = 128; off > 0; off >>= 1) {
        if (threadIdx.x < off)
            for (int k = 0; k < HID; ++k)
                smem[threadIdx.x][k] += smem[threadIdx.x + off][k];
        __syncthreads();
    }
    if (threadIdx.x == 0) {
        float inv = cnt > 0 ? 1.f / (float)cnt : 0.f;
        float hg[HID];
        for (int k = 0; k < HID; ++k) hg[k] = smem[0][k] * inv;
        float f1[FCH];
        for (int j = 0; j < FCH; ++j) {
            float a = bf1[j];
            for (int k = 0; k < HID; ++k) a += hg[k] * Wf1[k * FCH + j];
            f1[j] = a;
        }
        float o = bf2[0];
        for (int j = 0; j < FCH; ++j) o += f1[j] * Wf2[j];
        out[g] = 1.f / (1.f + expf(-o));
    }
}

extern "C" void kernel_launch(void* const* d_in, const int* in_sizes, int n_in,
                              void* d_out, int out_size, void* d_ws, size_t ws_size,
                              hipStream_t stream) {
    const float* h   = (const float*)d_in[0];
    const int*   src = (const int*)d_in[1];
    const int*   dst = (const int*)d_in[2];
    const int*   gid = (const int*)d_in[3];
    const float* W1  = (const float*)d_in[4];
    const float* b1  = (const float*)d_in[5];
    const float* W2  = (const float*)d_in[6];
    const float* b2  = (const float*)d_in[7];
    const float* Wf1 = (const float*)d_in[8];
    const float* bf1 = (const float*)d_in[9];
    const float* Wf2 = (const float*)d_in[10];
    const float* bf2 = (const float*)d_in[11];
    float* out = (float*)d_out;

    int n  = in_sizes[3];
    int ne = in_sizes[1];

    size_t featB16 = (size_t)n * HID * 2;        // 32 MB (bf16 features)
    size_t featB32 = (size_t)n * HID * 4;        // 64 MB (fallback)
    size_t edgeB   = (size_t)ne * 4;             // 64 MB
    size_t slot2   = featB16 > edgeB ? featB16 : edgeB;  // bufB / packed alias
    int NB  = (n + NPB - 1) / NPB;
    int NBS = NB * NBLK;
    int nbS = (NBS + 255) / 256;

    size_t off_bufA   = 0;
    size_t off_slot2  = off_bufA + featB16;
    size_t off_csr    = off_slot2 + slot2;
    size_t off_histT  = off_csr + edgeB;
    size_t off_histTT = off_histT + (size_t)NBS * 4;
    size_t off_rowoff = off_histTT + (size_t)NPB * NBLK * 4;
    size_t off_bsums  = off_rowoff + (size_t)(n + 1) * 4;
    size_t need       = off_bsums + 4096 * 4;

    char* ws = (char*)d_ws;
    if (ws_size >= need && n <= (1 << 20) && NB <= NPB && nbS <= 4096) {
        // ---------- radix-CSR + bf16 gather path (best known structure) ----
        bf16*  bufA   = (bf16*)(ws + off_bufA);
        bf16*  bufB   = (bf16*)(ws + off_slot2);
        int*   packed = (int*) (ws + off_slot2);   // alias: dead before agg1
        int*   csr    = (int*) (ws + off_csr);
        int*   histT  = (int*) (ws + off_histT);
        int*   histTT = (int*) (ws + off_histTT);
        int*   rowoff = (int*) (ws + off_rowoff);
        int*   bsums  = (int*) (ws + off_bsums);

        int chunk = (ne + NBLK - 1) / NBLK;
        int ntile = (n * 4 + 255) / 256;
        int aggGrid = ntile < 2048 ? ntile : 2048;
        int gN = (n + 255) / 256;

        proj1_kernel<<<gN, 256, 0, stream>>>(h, W1, bufA, n);
        hist_kernel<<<NBLK, 1024, 0, stream>>>(dst, histT, ne, NB, chunk);
        scan_block_kernel<<<nbS, 256, 0, stream>>>(histT, histT, bsums, NBS);
        scan_sums_kernel<<<1, 1024, 0, stream>>>(bsums, nbS);
        scan_add_kernel<<<nbS, 256, 0, stream>>>(histT, bsums, histTT, NBS);
        partition_kernel<<<PBLK, 1024, 0, stream>>>(src, dst, histTT, packed, ne, NB, chunk);
        csr_build_kernel<<<NB, 1024, 0, stream>>>(histT, packed, csr, rowoff, n, ne, NB);
        agg_kernel<true><<<aggGrid, 256, 0, stream>>>(rowoff, csr, bufA, b1, W2, bufB, n);
        agg_kernel<false><<<aggGrid, 256, 0, stream>>>(rowoff, csr, bufB, b2, nullptr, bufA, n);
        pool_fc_bf16_kernel<<<NG, 256, 0, stream>>>(bufA, gid, n, Wf1, bf1, Wf2, bf2, out);
    } else {
        // ---------- fallback: fp32 atomic scatter path ----------
        float* bufA = (float*)ws;
        float* bufB = (float*)(ws + featB32);
        float* degF = (float*)(ws + 2 * featB32);

        hipMemsetAsync(bufB, 0, featB32, stream);
        hipMemsetAsync(degF, 0, (size_t)n * 4, stream);

        proj1_f32_kernel<<<4096, 256, 0, stream>>>(h, W1, bufA, n);
        scatter_kernel<true><<<8192, 256, 0, stream>>>(src, dst, bufA, bufB, degF, ne);
        finish1_kernel<<<4096, 256, 0, stream>>>(bufB, degF, bufA, b1, W2, n);
        hipMemsetAsync(bufB, 0, featB32, stream);
        scatter_kernel<false><<<8192, 256, 0, stream>>>(src, dst, bufA, bufB, degF, ne);
        finish2_kernel<<<4096, 256, 0, stream>>>(bufB, degF, bufA, b2, n);
        pool_fc_f32_kernel<<<NG, 256, 0, stream>>>(bufA, gid, n, Wf1, bf1, Wf2, bf2, out);
    }
}